// Round 4
// baseline (1543.621 us; speedup 1.0000x reference)
//
#include <hip/hip_runtime.h>
#include <hip/hip_bf16.h>

// DenoisingPotential: x_{t+1} = x_t + alpha * grad_phi(x_t), 10 iters.
// grad = -(sum_k w_k * (P_k x - P_k mu_k)),  w = softmax(c - 0.5*quad)
// Restructured: s_k = e_k + (Pmu_k . x) - 0.5*(x . y_k), y_k = P_k x
// x += (alpha/l) * (sum_k wt_k Pmu_k - sum_k wt_k y_k),  wt = exp(s), l = sum wt
// (c=0 and quad>=0 => s<=0: no softmax max-shift needed)
//
// R4: R1 (barrier staging) and R3 (register dbuf) both stall at ~1870
// cyc/CU-k-step -> common limiter is latency chains at 2 waves/SIMD (supply
// cap of 32 pts/wave). This round: 16 pts/wave -> 16 waves/CU (4/SIMD),
// block-shared P staging via global_load_lds with the barrier BEFORE the DMA
// issue (the vmcnt(0) drain inside __syncthreads then only waits on DMAs
// issued a full k-step earlier -> race-free AND no exposed L2 latency).

typedef __attribute__((ext_vector_type(4))) float f32x4;
typedef __attribute__((ext_vector_type(8))) short bf16x8;  // 8 bf16 = 4 VGPRs

#define KC 32
#define NITER 10

typedef __attribute__((address_space(3))) void as3_void;
typedef __attribute__((address_space(1))) const void as1_cvoid;

static __device__ __forceinline__ void gl_lds16(const void* g, void* l) {
  // per-lane gptr; LDS dest = wave-uniform base + lane*16 (HW semantics)
  __builtin_amdgcn_global_load_lds((as1_cvoid*)g, (as3_void*)l, 16, 0, 0);
}

static __device__ __forceinline__ unsigned pk_bf16(float a, float b) {
  __hip_bfloat16 ha = __float2bfloat16(a), hb = __float2bfloat16(b);
  unsigned short ua = *(unsigned short*)&ha, ub = *(unsigned short*)&hb;
  return (unsigned)ua | ((unsigned)ub << 16);
}

static __device__ __forceinline__ unsigned short bf_bits(float a) {
  __hip_bfloat16 h = __float2bfloat16(a);
  return *(unsigned short*)&h;
}

// ---------------- precompute 1: per-k P = A^T A, Pmu, e, swizzled P ----------
__global__ void precompute1(const float* __restrict__ A, const float* __restrict__ mu,
                            const float* __restrict__ c,
                            float* __restrict__ Pmu_g, float* __restrict__ e_g,
                            __hip_bfloat16* __restrict__ Psw) {
  __shared__ float Pk[64 * 64];
  __shared__ float Pmu_s[64];
  const int k = blockIdx.x, tid = threadIdx.x;
  const float* Ak = A + k * 4096;
  for (int idx = tid; idx < 4096; idx += 256) {
    int i = idx >> 6, l = idx & 63;
    float s = 0.f;
    for (int j = 0; j < 64; ++j) s += Ak[j * 64 + i] * Ak[j * 64 + l];
    Pk[idx] = s;  // P[i][l], exactly symmetric
  }
  __syncthreads();
  if (tid < 64) {
    float s = 0.f;
    for (int l = 0; l < 64; ++l) s += Pk[tid * 64 + l] * mu[k * 64 + l];
    Pmu_s[tid] = s;
    Pmu_g[k * 64 + tid] = s;
  }
  __syncthreads();
  if (tid == 0) {
    float s = 0.f;
    for (int i = 0; i < 64; ++i) s += mu[k * 64 + i] * Pmu_s[i];
    e_g[k] = c[k] - 0.5f * s;
  }
  // A-frag order for the main GEMM: flat idx = f*512 + lane*8 + j,
  // f=(mt,s): val = P[dim_in = s*32 + q*8 + j][dim_out = mt*16 + l4]
  for (int idx = tid; idx < 4096; idx += 256) {
    int f = idx >> 9, lane = (idx >> 3) & 63, j = idx & 7;
    int mt = f >> 1, s = f & 1, qq = lane >> 4, l4 = lane & 15;
    float v = Pk[(s * 32 + qq * 8 + j) * 64 + mt * 16 + l4];
    Psw[k * 4096 + idx] = __float2bfloat16(v);
  }
}

// ---------------- precompute 2: Pmu fragment swizzles -----------------------
__global__ void precompute2(const float* __restrict__ Pmu_g,
                            __hip_bfloat16* __restrict__ PmuA,
                            __hip_bfloat16* __restrict__ PmuB) {
  const int tid = threadIdx.x;
  // PmuA (pmx GEMM A-operand): A[m=cluster][kk=dim]; frag f=(mtc,s)
  for (int idx = tid; idx < 2048; idx += 256) {
    int f = idx >> 9, lane = (idx >> 3) & 63, j = idx & 7;
    int mtc = f >> 1, s = f & 1, qq = lane >> 4, l4 = lane & 15;
    PmuA[idx] = __float2bfloat16(Pmu_g[(mtc * 16 + l4) * 64 + s * 32 + qq * 8 + j]);
  }
  // PmuB (pacc GEMM A-operand): A[m=dim][kk=cluster]; frag f=mtd (K=32, 1 step)
  for (int idx = tid; idx < 2048; idx += 256) {
    int f = idx >> 9, lane = (idx >> 3) & 63, j = idx & 7;
    int qq = lane >> 4, l4 = lane & 15;
    PmuB[idx] = __float2bfloat16(Pmu_g[(qq * 8 + j) * 64 + f * 16 + l4]);
  }
}

// ---------------- main kernel ----------------------------------------------
// 256 thr (4 waves), 16 pts/wave, 64 pts/block, grid 1024 -> 4 blocks/CU =
// 16 waves/CU (4 per SIMD). P tile block-shared in LDS, staged by all 4 waves
// (2 chunks each). One __syncthreads per k, placed BEFORE the DMA issue.
__launch_bounds__(256, 4)
__global__ void denoise_main(const float* __restrict__ x_in,
                             const float* __restrict__ e_g,
                             const float* __restrict__ alpha_g,
                             const __hip_bfloat16* __restrict__ Psw,
                             const __hip_bfloat16* __restrict__ PmuA,
                             const __hip_bfloat16* __restrict__ PmuB,
                             float* __restrict__ out) {
  __shared__ __attribute__((aligned(16))) __hip_bfloat16 pbuf[2 * 4096];  // 16 KB
  __shared__ __attribute__((aligned(16))) char scratch[4 * 2048];         // 8 KB

  const int tid = threadIdx.x;
  const int wave = tid >> 6, lane = tid & 63;
  const int q = lane >> 4, l4 = lane & 15;
  const int base_pt = blockIdx.x * 64 + wave * 16;
  const float alpha = alpha_g[0];

  char* sw = scratch + wave * 2048;        // per-wave scratch
  float* pmxw = (float*)sw;                // pmx[cluster=32][pt=16] f32 (overlays xs)

  const bf16x8* PmuAF = (const bf16x8*)PmuA;  // frag idx = f*64 + lane
  const bf16x8* PmuBF = (const bf16x8*)PmuB;

  // x master, C-layout: xm[mt][r] = x[dim = mt*16+q*4+r][pt = base_pt+l4]
  float xm[4][4];
#pragma unroll
  for (int mt = 0; mt < 4; ++mt) {
    f32x4 v = *(const f32x4*)&x_in[(base_pt + l4) * 64 + mt * 16 + q * 4];
#pragma unroll
    for (int r = 0; r < 4; ++r) xm[mt][r] = v[r];
  }

  const f32x4 Z4 = {0.f, 0.f, 0.f, 0.f};

#pragma unroll 1
  for (int it = 0; it < NITER; ++it) {
    // ---- stage x (bf16) into per-wave rows [pt=16][dim=64], 128 B rows,
    // 16B-block XOR swizzle (cb ^= row&7) to spread banks ----
#pragma unroll
    for (int mt = 0; mt < 4; ++mt) {
      unsigned u0 = pk_bf16(xm[mt][0], xm[mt][1]);
      unsigned u1 = pk_bf16(xm[mt][2], xm[mt][3]);
      int cb = mt * 2 + (q >> 1);
      int addr = l4 * 128 + ((cb ^ (l4 & 7)) << 4) + (q & 1) * 8;
      uint2 v; v.x = u0; v.y = u1;
      *(uint2*)(sw + addr) = v;
    }

    // ---- B-frags of x: B[kk=dim=s*32+q*8+j][n=pt=l4] (constant over k) ----
    bf16x8 bx[2];
#pragma unroll
    for (int s = 0; s < 2; ++s) {
      int cb = s * 4 + q;
      bx[s] = *(const bf16x8*)(sw + l4 * 128 + ((cb ^ (l4 & 7)) << 4));
    }

    // ---- PmuA fragment loads (vmem, issued before the DMA below) ----
    bf16x8 apa[4];
#pragma unroll
    for (int f = 0; f < 4; ++f) apa[f] = PmuAF[f * 64 + lane];

    // ---- DMA tile 0 into buf0 (each wave stages its 2 KB quarter) ----
    {
      const char* g = (const char*)Psw + wave * 2048 + lane * 16;
      char* l = (char*)&pbuf[0] + wave * 2048;
      gl_lds16(g, l);
      gl_lds16(g + 1024, l + 1024);
    }

    // ---- pmx GEMM: pmx[cluster][pt] = sum_dim Pmu[cluster][dim]*x[dim][pt] ----
    f32x4 pmx[2];
#pragma unroll
    for (int mtc = 0; mtc < 2; ++mtc) {
      f32x4 acc = Z4;
      acc = __builtin_amdgcn_mfma_f32_16x16x32_bf16(apa[mtc * 2 + 0], bx[0], acc, 0, 0, 0);
      acc = __builtin_amdgcn_mfma_f32_16x16x32_bf16(apa[mtc * 2 + 1], bx[1], acc, 0, 0, 0);
      pmx[mtc] = acc;
    }
    // spill pmx to per-wave LDS [cluster][pt] f32 (xs region dead after bx)
#pragma unroll
    for (int mtc = 0; mtc < 2; ++mtc)
#pragma unroll
      for (int r = 0; r < 4; ++r)
        pmxw[(mtc * 16 + q * 4 + r) * 16 + l4] = pmx[mtc][r];

    float accY[4][4];
#pragma unroll
    for (int mt = 0; mt < 4; ++mt)
#pragma unroll
      for (int r = 0; r < 4; ++r) accY[mt][r] = 0.f;
    float lsum = 0.f;
    float wk[8];  // lane quad g2 keeps w for k in [8*g2, 8*g2+8)
#pragma unroll
    for (int u = 0; u < 8; ++u) wk[u] = 0.f;

    // ---- k-loop: shared LDS dbuf; barrier BEFORE next-tile DMA issue ----
#pragma unroll 1
    for (int g2 = 0; g2 < 4; ++g2) {
#pragma unroll
      for (int u = 0; u < 8; ++u) {
        const int k = g2 * 8 + u;
        const int buf = u & 1;  // (g2*8+u)&1 == u&1
        // Drain (vmcnt covers tile-k DMAs issued one step ago -> already
        // landed) + join: tile k fully visible, tile k-1 reads all complete.
        __syncthreads();
        if (k < KC - 1) {
          const char* g = (const char*)Psw + (k + 1) * 8192 + wave * 2048 + lane * 16;
          char* l = (char*)&pbuf[0] + (buf ^ 1) * 4096 * 2 + wave * 2048;
          gl_lds16(g, l);
          gl_lds16(g + 1024, l + 1024);
        }
        // A-frags of P: A[m=dim_out=mt*16+l4][kk=dim_in=s*32+q*8+j]
        const char* pb = (const char*)&pbuf[buf * 4096];
        bf16x8 ap[4][2];
#pragma unroll
        for (int mt = 0; mt < 4; ++mt)
#pragma unroll
          for (int s = 0; s < 2; ++s)
            ap[mt][s] = *(const bf16x8*)(pb + (mt * 2 + s) * 1024 + lane * 16);

        // y = P x : C[row=dim=mt*16+q*4+r][col=pt=l4]
        f32x4 y[4];
#pragma unroll
        for (int mt = 0; mt < 4; ++mt) {
          f32x4 acc = Z4;
          acc = __builtin_amdgcn_mfma_f32_16x16x32_bf16(ap[mt][0], bx[0], acc, 0, 0, 0);
          acc = __builtin_amdgcn_mfma_f32_16x16x32_bf16(ap[mt][1], bx[1], acc, 0, 0, 0);
          y[mt] = acc;
        }

        // xy = x . y (16 partials in-lane, then cross-quad reduce)
        float xy = 0.f;
#pragma unroll
        for (int mt = 0; mt < 4; ++mt)
#pragma unroll
          for (int r = 0; r < 4; ++r) xy += xm[mt][r] * y[mt][r];
        xy += __shfl_xor(xy, 16, 64);
        xy += __shfl_xor(xy, 32, 64);

        const float pk = pmxw[k * 16 + l4];
        const float w = __expf(e_g[k] + pk - 0.5f * xy);
        lsum += w;
        wk[u] = (q == g2) ? w : wk[u];
#pragma unroll
        for (int mt = 0; mt < 4; ++mt)
#pragma unroll
          for (int r = 0; r < 4; ++r) accY[mt][r] += w * y[mt][r];
      }
    }

    // ---- pacc[dim][pt] = sum_k Pmu[k][dim] * wt[k][pt]  (one K=32 GEMM) ----
    // B-frag element j = w[kk=q*8+j][pt=l4] == wk[j] by construction.
    union { bf16x8 v; unsigned short s[8]; } uw;
#pragma unroll
    for (int j = 0; j < 8; ++j) uw.s[j] = bf_bits(wk[j]);
    f32x4 pacc[4];
#pragma unroll
    for (int mt = 0; mt < 4; ++mt) {
      bf16x8 a = PmuBF[mt * 64 + lane];
      pacc[mt] = __builtin_amdgcn_mfma_f32_16x16x32_bf16(a, uw.v, Z4, 0, 0, 0);
    }

    // ---- x += (alpha/l) * (pacc - accY) ----
    const float cc = alpha / lsum;
#pragma unroll
    for (int mt = 0; mt < 4; ++mt)
#pragma unroll
      for (int r = 0; r < 4; ++r)
        xm[mt][r] += cc * (pacc[mt][r] - accY[mt][r]);
  }  // iterations

  // ---- output: vectorized direct stores (16 B per lane per mt) ----
#pragma unroll
  for (int mt = 0; mt < 4; ++mt) {
    f32x4 v;
#pragma unroll
    for (int r = 0; r < 4; ++r) v[r] = xm[mt][r];
    *(f32x4*)&out[(base_pt + l4) * 64 + mt * 16 + q * 4] = v;
  }
}

extern "C" void kernel_launch(void* const* d_in, const int* in_sizes, int n_in,
                              void* d_out, int out_size, void* d_ws, size_t ws_size,
                              hipStream_t stream) {
  (void)in_sizes; (void)n_in; (void)out_size; (void)ws_size;
  const float* x = (const float*)d_in[0];
  const float* c = (const float*)d_in[1];
  const float* mu = (const float*)d_in[2];
  const float* A = (const float*)d_in[3];
  const float* alpha = (const float*)d_in[4];
  float* out = (float*)d_out;

  char* ws = (char*)d_ws;
  float* Pmu_g = (float*)(ws);                           // 8192 B
  float* e_g = (float*)(ws + 8192);                      // 128 B (pad to 256)
  __hip_bfloat16* PmuA = (__hip_bfloat16*)(ws + 8448);   // 4096 B
  __hip_bfloat16* PmuB = (__hip_bfloat16*)(ws + 12544);  // 4096 B
  __hip_bfloat16* Psw = (__hip_bfloat16*)(ws + 16640);   // 262144 B

  precompute1<<<32, 256, 0, stream>>>(A, mu, c, Pmu_g, e_g, Psw);
  precompute2<<<1, 256, 0, stream>>>(Pmu_g, PmuA, PmuB);
  denoise_main<<<1024, 256, 0, stream>>>(x, e_g, alpha, Psw, PmuA, PmuB, out);
}

// Round 5
// 350.988 us; speedup vs baseline: 4.3979x; 4.3979x over previous
//
#include <hip/hip_runtime.h>
#include <hip/hip_bf16.h>

// DenoisingPotential: x_{t+1} = x_t + alpha * grad_phi(x_t), 10 iters.
// grad = -(sum_k w_k * (P_k x - P_k mu_k)),  w = softmax(c - 0.5*quad)
// Restructured: s_k = e_k + (Pmu_k . x) - 0.5*(x . y_k), y_k = P_k x
// x += (alpha/l) * (sum_k wt_k Pmu_k - sum_k wt_k y_k),  wt = exp(s), l = sum wt
// (c=0 and quad>=0 => s<=0: no softmax max-shift needed)
//
// R5: R4's structure (16 pts/wave, 4 blocks/CU, barrier-before-DMA pipelined
// P staging) was right but spilled (WRITE_SIZE 4.3 GB of scratch traffic at
// VGPR cap 128). This round keeps the structure and deletes the pressure:
// no register weight-capture (weights -> wave-private LDS), no A-frag
// register block (ds_read_b128 directly at the MFMAs), unroll 2 only,
// hand-treed dot to shorten the per-k dependency chain.

typedef __attribute__((ext_vector_type(4))) float f32x4;
typedef __attribute__((ext_vector_type(8))) short bf16x8;  // 8 bf16 = 4 VGPRs

#define KC 32
#define NITER 10

typedef __attribute__((address_space(3))) void as3_void;
typedef __attribute__((address_space(1))) const void as1_cvoid;

static __device__ __forceinline__ void gl_lds16(const void* g, void* l) {
  // per-lane gptr; LDS dest = wave-uniform base + lane*16 (HW semantics)
  __builtin_amdgcn_global_load_lds((as1_cvoid*)g, (as3_void*)l, 16, 0, 0);
}

static __device__ __forceinline__ unsigned pk_bf16(float a, float b) {
  __hip_bfloat16 ha = __float2bfloat16(a), hb = __float2bfloat16(b);
  unsigned short ua = *(unsigned short*)&ha, ub = *(unsigned short*)&hb;
  return (unsigned)ua | ((unsigned)ub << 16);
}

// ---------------- precompute 1: per-k P = A^T A, Pmu, e, swizzled P ----------
__global__ void precompute1(const float* __restrict__ A, const float* __restrict__ mu,
                            const float* __restrict__ c,
                            float* __restrict__ Pmu_g, float* __restrict__ e_g,
                            __hip_bfloat16* __restrict__ Psw) {
  __shared__ float Pk[64 * 64];
  __shared__ float Pmu_s[64];
  const int k = blockIdx.x, tid = threadIdx.x;
  const float* Ak = A + k * 4096;
  for (int idx = tid; idx < 4096; idx += 256) {
    int i = idx >> 6, l = idx & 63;
    float s = 0.f;
    for (int j = 0; j < 64; ++j) s += Ak[j * 64 + i] * Ak[j * 64 + l];
    Pk[idx] = s;  // P[i][l], exactly symmetric
  }
  __syncthreads();
  if (tid < 64) {
    float s = 0.f;
    for (int l = 0; l < 64; ++l) s += Pk[tid * 64 + l] * mu[k * 64 + l];
    Pmu_s[tid] = s;
    Pmu_g[k * 64 + tid] = s;
  }
  __syncthreads();
  if (tid == 0) {
    float s = 0.f;
    for (int i = 0; i < 64; ++i) s += mu[k * 64 + i] * Pmu_s[i];
    e_g[k] = c[k] - 0.5f * s;
  }
  // A-frag order for the main GEMM: flat idx = f*512 + lane*8 + j,
  // f=(mt,s): val = P[dim_in = s*32 + q*8 + j][dim_out = mt*16 + l4]
  for (int idx = tid; idx < 4096; idx += 256) {
    int f = idx >> 9, lane = (idx >> 3) & 63, j = idx & 7;
    int mt = f >> 1, s = f & 1, qq = lane >> 4, l4 = lane & 15;
    float v = Pk[(s * 32 + qq * 8 + j) * 64 + mt * 16 + l4];
    Psw[k * 4096 + idx] = __float2bfloat16(v);
  }
}

// ---------------- precompute 2: Pmu fragment swizzles -----------------------
__global__ void precompute2(const float* __restrict__ Pmu_g,
                            __hip_bfloat16* __restrict__ PmuA,
                            __hip_bfloat16* __restrict__ PmuB) {
  const int tid = threadIdx.x;
  // PmuA (pmx GEMM A-operand): A[m=cluster][kk=dim]; frag f=(mtc,s)
  for (int idx = tid; idx < 2048; idx += 256) {
    int f = idx >> 9, lane = (idx >> 3) & 63, j = idx & 7;
    int mtc = f >> 1, s = f & 1, qq = lane >> 4, l4 = lane & 15;
    PmuA[idx] = __float2bfloat16(Pmu_g[(mtc * 16 + l4) * 64 + s * 32 + qq * 8 + j]);
  }
  // PmuB (pacc GEMM A-operand): A[m=dim][kk=cluster]; frag f=mtd (K=32, 1 step)
  for (int idx = tid; idx < 2048; idx += 256) {
    int f = idx >> 9, lane = (idx >> 3) & 63, j = idx & 7;
    int qq = lane >> 4, l4 = lane & 15;
    PmuB[idx] = __float2bfloat16(Pmu_g[(qq * 8 + j) * 64 + f * 16 + l4]);
  }
}

// ---------------- main kernel ----------------------------------------------
// 256 thr (4 waves), 16 pts/wave, 64 pts/block, grid 1024 -> 4 blocks/CU =
// 16 waves/CU (4 per SIMD). P tile block-shared in LDS (8 KB/tile, dbuf),
// each wave DMAs its 2 KB quarter. One __syncthreads per k, BEFORE the DMA
// issue: its vmcnt(0) drain only waits on DMAs issued a full k-step earlier.
__launch_bounds__(256, 4)
__global__ void denoise_main(const float* __restrict__ x_in,
                             const float* __restrict__ e_g,
                             const float* __restrict__ alpha_g,
                             const __hip_bfloat16* __restrict__ Psw,
                             const __hip_bfloat16* __restrict__ PmuA,
                             const __hip_bfloat16* __restrict__ PmuB,
                             float* __restrict__ out) {
  __shared__ __attribute__((aligned(16))) char pbuf[2 * 8192];     // P dbuf 16 KB
  __shared__ __attribute__((aligned(16))) char scratch[4 * 3072];  // 12 KB

  const int tid = threadIdx.x;
  const int wave = tid >> 6, lane = tid & 63;
  const int q = lane >> 4, l4 = lane & 15;
  const int base_pt = blockIdx.x * 64 + wave * 16;
  const float alpha = alpha_g[0];

  char* sw = scratch + wave * 3072;                    // per-wave scratch
  float* pmxw = (float*)sw;                            // pmx[cl=32][pt=16] f32, 2 KB (overlays xs)
  __hip_bfloat16* wtw = (__hip_bfloat16*)(sw + 2048);  // wt[pt=16][k=32] bf16, 1 KB

  const bf16x8* PmuAF = (const bf16x8*)PmuA;  // frag idx = f*64 + lane
  const bf16x8* PmuBF = (const bf16x8*)PmuB;

  // x master, C-layout: xm[mt][r] = x[dim = mt*16+q*4+r][pt = base_pt+l4]
  float xm[4][4];
#pragma unroll
  for (int mt = 0; mt < 4; ++mt) {
    f32x4 v = *(const f32x4*)&x_in[(base_pt + l4) * 64 + mt * 16 + q * 4];
#pragma unroll
    for (int r = 0; r < 4; ++r) xm[mt][r] = v[r];
  }

  const f32x4 Z4 = {0.f, 0.f, 0.f, 0.f};

#pragma unroll 1
  for (int it = 0; it < NITER; ++it) {
    // ---- stage x (bf16) into per-wave rows [pt=16][dim=64] (128 B rows,
    // 16B-block XOR swizzle to spread banks) ----
#pragma unroll
    for (int mt = 0; mt < 4; ++mt) {
      unsigned u0 = pk_bf16(xm[mt][0], xm[mt][1]);
      unsigned u1 = pk_bf16(xm[mt][2], xm[mt][3]);
      int cb = mt * 2 + (q >> 1);
      int addr = l4 * 128 + ((cb ^ (l4 & 7)) << 4) + (q & 1) * 8;
      uint2 v; v.x = u0; v.y = u1;
      *(uint2*)(sw + addr) = v;
    }

    // ---- B-frags of x: B[kk=dim=s*32+q*8+j][n=pt=l4] (constant over k) ----
    bf16x8 bx[2];
#pragma unroll
    for (int s = 0; s < 2; ++s) {
      int cb = s * 4 + q;
      bx[s] = *(const bf16x8*)(sw + l4 * 128 + ((cb ^ (l4 & 7)) << 4));
    }

    // ---- DMA tile 0 into buf0 (each wave stages its 2 KB quarter) ----
    {
      const char* g = (const char*)Psw + wave * 2048 + lane * 16;
      char* l = pbuf + wave * 2048;
      gl_lds16(g, l);
      gl_lds16(g + 1024, l + 1024);
    }

    // ---- pmx GEMM: pmx[cluster][pt] = sum_dim Pmu[cluster][dim]*x[dim][pt] ----
#pragma unroll
    for (int mtc = 0; mtc < 2; ++mtc) {
      f32x4 acc = Z4;
      acc = __builtin_amdgcn_mfma_f32_16x16x32_bf16(PmuAF[(mtc * 2 + 0) * 64 + lane], bx[0], acc, 0, 0, 0);
      acc = __builtin_amdgcn_mfma_f32_16x16x32_bf16(PmuAF[(mtc * 2 + 1) * 64 + lane], bx[1], acc, 0, 0, 0);
      // spill to per-wave LDS [cluster][pt] f32 (xs region dead after bx)
#pragma unroll
      for (int r = 0; r < 4; ++r)
        pmxw[(mtc * 16 + q * 4 + r) * 16 + l4] = acc[r];
    }

    float accY[4][4];
#pragma unroll
    for (int mt = 0; mt < 4; ++mt)
#pragma unroll
      for (int r = 0; r < 4; ++r) accY[mt][r] = 0.f;
    float lsum = 0.f;

    // ---- k-loop: shared LDS dbuf; barrier BEFORE next-tile DMA issue ----
#pragma unroll 2
    for (int k = 0; k < KC; ++k) {
      // Drain (vmcnt covers tile-k DMAs issued one step ago -> already
      // landed) + join: tile k fully visible; tile k-1 reads all complete.
      __syncthreads();
      if (k < KC - 1) {
        const char* g = (const char*)Psw + (k + 1) * 8192 + wave * 2048 + lane * 16;
        char* l = pbuf + ((k + 1) & 1) * 8192 + wave * 2048;
        gl_lds16(g, l);
        gl_lds16(g + 1024, l + 1024);
      }

      // y = P x : C[row=dim=mt*16+q*4+r][col=pt=l4], A-frags read straight
      // from LDS (contiguous 1 KB per frag -> conflict-free b128)
      const char* pb = pbuf + (k & 1) * 8192;
      f32x4 y[4];
#pragma unroll
      for (int mt = 0; mt < 4; ++mt) {
        f32x4 acc = Z4;
        acc = __builtin_amdgcn_mfma_f32_16x16x32_bf16(
            *(const bf16x8*)(pb + (mt * 2 + 0) * 1024 + lane * 16), bx[0], acc, 0, 0, 0);
        acc = __builtin_amdgcn_mfma_f32_16x16x32_bf16(
            *(const bf16x8*)(pb + (mt * 2 + 1) * 1024 + lane * 16), bx[1], acc, 0, 0, 0);
        y[mt] = acc;
      }

      // xy = x . y : 16 products, explicit depth-4 tree (short dep chain)
      float p[16];
#pragma unroll
      for (int i = 0; i < 16; ++i) p[i] = xm[i >> 2][i & 3] * y[i >> 2][i & 3];
#pragma unroll
      for (int st = 8; st > 0; st >>= 1)
#pragma unroll
        for (int i = 0; i < st; ++i) p[i] += p[i + st];
      float xy = p[0];
      xy += __shfl_xor(xy, 16, 64);
      xy += __shfl_xor(xy, 32, 64);

      const float pk = pmxw[k * 16 + l4];
      const float w = __expf(e_g[k] + pk - 0.5f * xy);
      lsum += w;
      if (q == 0) wtw[l4 * 32 + k] = __float2bfloat16(w);
#pragma unroll
      for (int mt = 0; mt < 4; ++mt)
#pragma unroll
        for (int r = 0; r < 4; ++r) accY[mt][r] += w * y[mt][r];
    }

    // ---- pacc[dim][pt] = sum_k Pmu[k][dim] * wt[k][pt]  (one K=32 GEMM) ----
    bf16x8 wtf = *(const bf16x8*)&wtw[l4 * 32 + q * 8];  // B[kk=q*8+j][n=pt=l4]
    const float cc = alpha / lsum;
#pragma unroll
    for (int mt = 0; mt < 4; ++mt) {
      f32x4 pacc = __builtin_amdgcn_mfma_f32_16x16x32_bf16(PmuBF[mt * 64 + lane], wtf, Z4, 0, 0, 0);
      // x += (alpha/l) * (pacc - accY)
#pragma unroll
      for (int r = 0; r < 4; ++r) xm[mt][r] += cc * (pacc[r] - accY[mt][r]);
    }
  }  // iterations

  // ---- output: vectorized direct stores (16 B per lane per mt) ----
#pragma unroll
  for (int mt = 0; mt < 4; ++mt) {
    f32x4 v;
#pragma unroll
    for (int r = 0; r < 4; ++r) v[r] = xm[mt][r];
    *(f32x4*)&out[(base_pt + l4) * 64 + mt * 16 + q * 4] = v;
  }
}

extern "C" void kernel_launch(void* const* d_in, const int* in_sizes, int n_in,
                              void* d_out, int out_size, void* d_ws, size_t ws_size,
                              hipStream_t stream) {
  (void)in_sizes; (void)n_in; (void)out_size; (void)ws_size;
  const float* x = (const float*)d_in[0];
  const float* c = (const float*)d_in[1];
  const float* mu = (const float*)d_in[2];
  const float* A = (const float*)d_in[3];
  const float* alpha = (const float*)d_in[4];
  float* out = (float*)d_out;

  char* ws = (char*)d_ws;
  float* Pmu_g = (float*)(ws);                           // 8192 B
  float* e_g = (float*)(ws + 8192);                      // 128 B (pad to 256)
  __hip_bfloat16* PmuA = (__hip_bfloat16*)(ws + 8448);   // 4096 B
  __hip_bfloat16* PmuB = (__hip_bfloat16*)(ws + 12544);  // 4096 B
  __hip_bfloat16* Psw = (__hip_bfloat16*)(ws + 16640);   // 262144 B

  precompute1<<<32, 256, 0, stream>>>(A, mu, c, Pmu_g, e_g, Psw);
  precompute2<<<1, 256, 0, stream>>>(Pmu_g, PmuA, PmuB);
  denoise_main<<<1024, 256, 0, stream>>>(x, e_g, alpha, Psw, PmuA, PmuB, out);
}

// Round 6
// 313.639 us; speedup vs baseline: 4.9217x; 1.1191x over previous
//
#include <hip/hip_runtime.h>
#include <hip/hip_bf16.h>

// DenoisingPotential: x_{t+1} = x_t + alpha * grad_phi(x_t), 10 iters.
// s_k = e_k + (Pmu_k . x) - 0.5*(x . y_k), y_k = P_k x
// x += (alpha/l) * (sum_k wt_k Pmu_k - sum_k wt_k y_k), wt = exp(s), l = sum wt
//
// R6: LDS-read traffic = waves/CU * 8KB/k-step is the wall (R5: 128KB -> 1900
// cyc). 32 pts/wave halves it (R1 org) + R5's barrier-before-DMA (kills R1's
// exposed L2 drain) + 32x32x16 MFMA everywhere (17% less MFMA-pipe time, one
// shfl instead of two in the quad-reduce). launch_bounds(256,2): ~180 VGPR.

typedef __attribute__((ext_vector_type(4))) float f32x4;
typedef __attribute__((ext_vector_type(16))) float f32x16;
typedef __attribute__((ext_vector_type(8))) short bf16x8;  // 8 bf16 = 4 VGPRs

#define KC 32
#define NITER 10
#define WAVE_SCR 6144  // per-wave scratch: xs/pmx 4096 + wt 2048

typedef __attribute__((address_space(3))) void as3_void;
typedef __attribute__((address_space(1))) const void as1_cvoid;

static __device__ __forceinline__ void gl_lds16(const void* g, void* l) {
  __builtin_amdgcn_global_load_lds((as1_cvoid*)g, (as3_void*)l, 16, 0, 0);
}

static __device__ __forceinline__ unsigned pk_bf16(float a, float b) {
  __hip_bfloat16 ha = __float2bfloat16(a), hb = __float2bfloat16(b);
  unsigned short ua = *(unsigned short*)&ha, ub = *(unsigned short*)&hb;
  return (unsigned)ua | ((unsigned)ub << 16);
}

// ---- precompute 1: P = A^T A, Pmu, e, P swizzled to 32x32x16 A-frag order --
// frag f = mt*4 + kf (mt: dim_out tile of 32, kf: K-frag of 16):
// Psw[k*4096 + f*512 + lane*8 + j] = P[kf*16 + (lane>>5)*8 + j][mt*32 + (lane&31)]
__global__ void precompute1(const float* __restrict__ A, const float* __restrict__ mu,
                            const float* __restrict__ c,
                            float* __restrict__ Pmu_g, float* __restrict__ e_g,
                            __hip_bfloat16* __restrict__ Psw) {
  __shared__ float Pk[64 * 64];
  __shared__ float Pmu_s[64];
  const int k = blockIdx.x, tid = threadIdx.x;
  const float* Ak = A + k * 4096;
  for (int idx = tid; idx < 4096; idx += 256) {
    int i = idx >> 6, l = idx & 63;
    float s = 0.f;
    for (int j = 0; j < 64; ++j) s += Ak[j * 64 + i] * Ak[j * 64 + l];
    Pk[idx] = s;
  }
  __syncthreads();
  if (tid < 64) {
    float s = 0.f;
    for (int l = 0; l < 64; ++l) s += Pk[tid * 64 + l] * mu[k * 64 + l];
    Pmu_s[tid] = s;
    Pmu_g[k * 64 + tid] = s;
  }
  __syncthreads();
  if (tid == 0) {
    float s = 0.f;
    for (int i = 0; i < 64; ++i) s += mu[k * 64 + i] * Pmu_s[i];
    e_g[k] = c[k] - 0.5f * s;
  }
  for (int idx = tid; idx < 4096; idx += 256) {
    int f = idx >> 9, lane = (idx >> 3) & 63, j = idx & 7;
    int mt = f >> 2, kf = f & 3, h = lane >> 5, l5 = lane & 31;
    float v = Pk[(kf * 16 + h * 8 + j) * 64 + mt * 32 + l5];
    Psw[k * 4096 + idx] = __float2bfloat16(v);
  }
}

// ---- precompute 2: Pmu fragment swizzles (32x32x16 A-frag order) ----------
__global__ void precompute2(const float* __restrict__ Pmu_g,
                            __hip_bfloat16* __restrict__ PmuA,
                            __hip_bfloat16* __restrict__ PmuB) {
  const int tid = threadIdx.x;
  // PmuA (pmx GEMM A): A[m=cluster=lane&31][k=dim=kf*16+h*8+j], f=kf (4 frags)
  for (int idx = tid; idx < 2048; idx += 256) {
    int f = idx >> 9, lane = (idx >> 3) & 63, j = idx & 7;
    int h = lane >> 5, l5 = lane & 31;
    PmuA[idx] = __float2bfloat16(Pmu_g[l5 * 64 + f * 16 + h * 8 + j]);
  }
  // PmuB (pacc GEMM A): A[m=dim=mt*32+(lane&31)][kk=cluster=kf*16+h*8+j],
  // f = mt*2+kf (4 frags)
  for (int idx = tid; idx < 2048; idx += 256) {
    int f = idx >> 9, lane = (idx >> 3) & 63, j = idx & 7;
    int mt = f >> 1, kf = f & 1, h = lane >> 5, l5 = lane & 31;
    PmuB[idx] = __float2bfloat16(Pmu_g[(kf * 16 + h * 8 + j) * 64 + mt * 32 + l5]);
  }
}

// ---- main kernel: 256 thr (4 waves), 32 pts/wave, grid 512 (2 blocks/CU) --
// P tile (8 KB) block-shared, double-buffered; one __syncthreads per k placed
// BEFORE the DMA issue (its vmcnt(0) drain covers only DMAs issued a full
// k-step earlier -> race-free, no exposed L2 latency).
__launch_bounds__(256, 2)
__global__ void denoise_main(const float* __restrict__ x_in,
                             const float* __restrict__ e_g,
                             const float* __restrict__ alpha_g,
                             const __hip_bfloat16* __restrict__ Psw,
                             const __hip_bfloat16* __restrict__ PmuA,
                             const __hip_bfloat16* __restrict__ PmuB,
                             float* __restrict__ out) {
  __shared__ __attribute__((aligned(16))) char pbuf[2 * 8192];        // 16 KB
  __shared__ __attribute__((aligned(16))) char scratch[4 * WAVE_SCR]; // 24 KB

  const int tid = threadIdx.x;
  const int wave = tid >> 6, lane = tid & 63;
  const int h = lane >> 5, l5 = lane & 31;
  const int base_pt = blockIdx.x * 128 + wave * 32;
  const int pt = base_pt + l5;
  const float alpha = alpha_g[0];

  char* sw = scratch + wave * WAVE_SCR;
  float* pmxw = (float*)sw;                            // [cl=32][pt=32] f32 4 KB (overlays xs)
  __hip_bfloat16* wtw = (__hip_bfloat16*)(sw + 4096);  // [pt=32][k=32] bf16 2 KB

  const bf16x8* PmuAF = (const bf16x8*)PmuA;  // frag idx = f*64 + lane
  const bf16x8* PmuBF = (const bf16x8*)PmuB;

  // x master in 32x32 C-layout: xm[mt][r] = x[dim = mt*32+(r&3)+8*(r>>2)+4*h][pt]
  float xm[2][16];
#pragma unroll
  for (int mt = 0; mt < 2; ++mt)
#pragma unroll
    for (int rq = 0; rq < 4; ++rq) {
      f32x4 v = *(const f32x4*)&x_in[pt * 64 + mt * 32 + rq * 8 + h * 4];
#pragma unroll
      for (int r = 0; r < 4; ++r) xm[mt][rq * 4 + r] = v[r];
    }

  const f32x16 Z16 = {0.f};

#pragma unroll 1
  for (int it = 0; it < NITER; ++it) {
    // ---- stage x (bf16) rows [pt][dim] (128 B rows, 16B-block XOR swizzle) --
#pragma unroll
    for (int mt = 0; mt < 2; ++mt)
#pragma unroll
      for (int rq = 0; rq < 4; ++rq) {
        // dims d0..d0+3, d0 = mt*32 + 8*rq + 4*h -> 8 B at block mt*4+rq, off 8h
        unsigned u0 = pk_bf16(xm[mt][rq * 4 + 0], xm[mt][rq * 4 + 1]);
        unsigned u1 = pk_bf16(xm[mt][rq * 4 + 2], xm[mt][rq * 4 + 3]);
        int blk = mt * 4 + rq;
        int addr = l5 * 128 + (((blk) ^ (l5 & 7)) << 4) + 8 * h;
        uint2 v; v.x = u0; v.y = u1;
        *(uint2*)(sw + addr) = v;
      }

    // ---- B-frags of x: bx[kf] = B[k=kf*16+h*8+j][n=pt] ----
    bf16x8 bx[4];
#pragma unroll
    for (int kf = 0; kf < 4; ++kf) {
      int blk = 2 * kf + h;
      bx[kf] = *(const bf16x8*)(sw + l5 * 128 + ((blk ^ (l5 & 7)) << 4));
    }

    // ---- DMA tile 0 into buf0 (each wave stages its 2 KB quarter) ----
    {
      const char* g = (const char*)Psw + wave * 2048 + lane * 16;
      char* l = pbuf + wave * 2048;
      gl_lds16(g, l);
      gl_lds16(g + 1024, l + 1024);
    }

    // ---- pmx GEMM (one 32x32 tile, K=64): pmx[cl][pt] ----
    {
      f32x16 acc = Z16;
#pragma unroll
      for (int kf = 0; kf < 4; ++kf)
        acc = __builtin_amdgcn_mfma_f32_32x32x16_bf16(PmuAF[kf * 64 + lane], bx[kf], acc, 0, 0, 0);
      // spill to LDS [cluster][pt] f32 (xs dead after bx)
#pragma unroll
      for (int r = 0; r < 16; ++r) {
        int cl = (r & 3) + 8 * (r >> 2) + 4 * h;
        pmxw[cl * 32 + l5] = acc[r];
      }
    }

    float accY[2][16];
#pragma unroll
    for (int mt = 0; mt < 2; ++mt)
#pragma unroll
      for (int r = 0; r < 16; ++r) accY[mt][r] = 0.f;
    float lsum = 0.f;

    // ---- k-loop: shared LDS dbuf; barrier BEFORE next-tile DMA issue ----
#pragma unroll 2
    for (int k = 0; k < KC; ++k) {
      __syncthreads();  // drains k-1's DMA (landed long ago) + joins waves
      if (k < KC - 1) {
        const char* g = (const char*)Psw + (k + 1) * 8192 + wave * 2048 + lane * 16;
        char* l = pbuf + ((k + 1) & 1) * 8192 + wave * 2048;
        gl_lds16(g, l);
        gl_lds16(g + 1024, l + 1024);
      }

      // y = P x : two 32x32 tiles (mt), K=64 (4 chained MFMAs each)
      const char* pb = pbuf + (k & 1) * 8192;
      f32x16 y[2];
#pragma unroll
      for (int mt = 0; mt < 2; ++mt) {
        f32x16 acc = Z16;
#pragma unroll
        for (int kf = 0; kf < 4; ++kf)
          acc = __builtin_amdgcn_mfma_f32_32x32x16_bf16(
              *(const bf16x8*)(pb + (mt * 4 + kf) * 1024 + lane * 16), bx[kf], acc, 0, 0, 0);
        y[mt] = acc;
      }

      // xy = x . y : 32 in-lane products (4 chains of 8), one shfl_xor(32)
      float p0 = 0.f, p1 = 0.f, p2 = 0.f, p3 = 0.f;
#pragma unroll
      for (int r = 0; r < 16; r += 4) {
        p0 += xm[0][r + 0] * y[0][r + 0] + xm[1][r + 0] * y[1][r + 0];
        p1 += xm[0][r + 1] * y[0][r + 1] + xm[1][r + 1] * y[1][r + 1];
        p2 += xm[0][r + 2] * y[0][r + 2] + xm[1][r + 2] * y[1][r + 2];
        p3 += xm[0][r + 3] * y[0][r + 3] + xm[1][r + 3] * y[1][r + 3];
      }
      float xy = (p0 + p1) + (p2 + p3);
      xy += __shfl_xor(xy, 32, 64);

      const float pk = pmxw[k * 32 + l5];
      const float w = __expf(e_g[k] + pk - 0.5f * xy);
      lsum += w;
      if (h == 0) wtw[l5 * 32 + k] = __float2bfloat16(w);
#pragma unroll
      for (int mt = 0; mt < 2; ++mt)
#pragma unroll
        for (int r = 0; r < 16; ++r) accY[mt][r] += w * y[mt][r];
    }

    // ---- pacc[dim][pt] = sum_cl Pmu[cl][dim]*wt[cl][pt] (32x32, K=32) ----
    bf16x8 wtf[2];
#pragma unroll
    for (int kf = 0; kf < 2; ++kf)
      wtf[kf] = *(const bf16x8*)&wtw[l5 * 32 + kf * 16 + h * 8];
    const float cc = alpha / lsum;
#pragma unroll
    for (int mt = 0; mt < 2; ++mt) {
      f32x16 acc = Z16;
      acc = __builtin_amdgcn_mfma_f32_32x32x16_bf16(PmuBF[(mt * 2 + 0) * 64 + lane], wtf[0], acc, 0, 0, 0);
      acc = __builtin_amdgcn_mfma_f32_32x32x16_bf16(PmuBF[(mt * 2 + 1) * 64 + lane], wtf[1], acc, 0, 0, 0);
#pragma unroll
      for (int r = 0; r < 16; ++r)
        xm[mt][r] += cc * (acc[r] - accY[mt][r]);
    }
  }  // iterations

  // ---- output: 8x f32x4 direct stores ----
#pragma unroll
  for (int mt = 0; mt < 2; ++mt)
#pragma unroll
    for (int rq = 0; rq < 4; ++rq) {
      f32x4 v;
#pragma unroll
      for (int r = 0; r < 4; ++r) v[r] = xm[mt][rq * 4 + r];
      *(f32x4*)&out[pt * 64 + mt * 32 + rq * 8 + h * 4] = v;
    }
}

extern "C" void kernel_launch(void* const* d_in, const int* in_sizes, int n_in,
                              void* d_out, int out_size, void* d_ws, size_t ws_size,
                              hipStream_t stream) {
  (void)in_sizes; (void)n_in; (void)out_size; (void)ws_size;
  const float* x = (const float*)d_in[0];
  const float* c = (const float*)d_in[1];
  const float* mu = (const float*)d_in[2];
  const float* A = (const float*)d_in[3];
  const float* alpha = (const float*)d_in[4];
  float* out = (float*)d_out;

  char* ws = (char*)d_ws;
  float* Pmu_g = (float*)(ws);                           // 8192 B
  float* e_g = (float*)(ws + 8192);                      // 128 B (pad to 256)
  __hip_bfloat16* PmuA = (__hip_bfloat16*)(ws + 8448);   // 4096 B
  __hip_bfloat16* PmuB = (__hip_bfloat16*)(ws + 12544);  // 4096 B
  __hip_bfloat16* Psw = (__hip_bfloat16*)(ws + 16640);   // 262144 B

  precompute1<<<32, 256, 0, stream>>>(A, mu, c, Pmu_g, e_g, Psw);
  precompute2<<<1, 256, 0, stream>>>(Pmu_g, PmuA, PmuB);
  denoise_main<<<512, 256, 0, stream>>>(x, e_g, alpha, Psw, PmuA, PmuB, out);
}